// Round 1
// 223.544 us; speedup vs baseline: 1.0061x; 1.0061x over previous
//
#include <hip/hip_runtime.h>

#define N_PTS 100000
#define KNB   12
#define TLEN  365
#define FUSED_ROWS 64
#define SYNTH_ROWS 16
#define PARAMS_BYTES ((size_t)N_PTS * 12 * sizeof(float))

// ENVIRONMENT FACTS (rounds 0-7):
//  - Inputs are bf16 (r3 runtime probe chose bf16 path, passed, absmax 0.0625
//    = bf16 quantization floor). idx int32.
//  - Round-3 kernel code is the ONLY proven-correct variant. Rounds 4-6
//    changed (a) smooth to 4-thread/pixel + (b) hard-coded bf16 -> NaN.
//    Mechanism unknown => compute_params (incl. all loads) is load-bearing;
//    change only launch geometry / non-load code.
//  - r7 (224.9 us): top-5 rocprof dispatches are ALL harness poison fills
//    (~87 us each @ 84% HBM peak). Our kernels are each <86.5 us and do not
//    appear => timed window ~= 2x87 fill + ~50 us ours.
//  - r8 (this round): single fused kernel, 64 thr/block, 64 rows/block,
//    1563 blocks. compute_params call pattern IDENTICAL (1 thread = 1 row,
//    runtime b16 flag). Removes global barrier between smooth/synth, params
//    round-trip, and second launch; blocks pipeline independently.

__device__ __forceinline__ float bf2f(unsigned short u) {
    return __uint_as_float(((unsigned int)u) << 16);
}
__device__ __forceinline__ unsigned short f2bf(float f) {
    unsigned int x = __float_as_uint(f);
    unsigned int r = (x + 0x7FFFu + ((x >> 16) & 1u)) >> 16;
    return (unsigned short)r;
}

// Runtime input-dtype detection: time_vector[0] == 0.0 exactly.
__device__ __forceinline__ bool detect_bf16(const void* tvec) {
    return ((const unsigned int*)tvec)[0] != 0u;
}

// Scalar dual-dtype load (round-3 proven).
__device__ __forceinline__ float ld(const void* p, size_t i, bool b16) {
    if (b16) return bf2f(((const unsigned short*)p)[i]);
    return ((const float*)p)[i];
}

// Param row for pixel n: [c, trend, a0..a3, b0..b3]  (round-3 verbatim)
__device__ void compute_params(
    int n, bool b16,
    const void* __restrict__ amps,
    const void* __restrict__ phs,
    const void* __restrict__ wgts,
    const int*  __restrict__ idx,
    const void* __restrict__ coff,
    const void* __restrict__ trend,
    float outp[12])
{
    float sx[4]  = {0,0,0,0}, sxx[4] = {0,0,0,0}, swx[4] = {0,0,0,0};
    float wre[4] = {0,0,0,0}, wim[4] = {0,0,0,0};

    #pragma unroll
    for (int k = 0; k < KNB; ++k) {
        int j = idx[(size_t)n * KNB + k];
        j = (j < 0) ? 0 : ((j >= N_PTS) ? N_PTS - 1 : j);  // defensive clamp
        float wk = ld(wgts, (size_t)n * KNB + k, b16);
        #pragma unroll
        for (int i = 0; i < 4; ++i) {
            float a = ld(amps, (size_t)j * 4 + i, b16);
            float p = ld(phs,  (size_t)j * 4 + i, b16);
            sx[i]  += a;
            sxx[i] += a * a;
            swx[i] += wk * a;
            float s, c;
            __sincosf(p, &s, &c);
            wre[i] += wk * c;
            wim[i] += wk * s;
        }
    }

    outp[0] = ld(coff,  n, b16);
    outp[1] = ld(trend, n, b16);
    #pragma unroll
    for (int i = 0; i < 4; ++i) {
        float aof = ld(amps, (size_t)n * 4 + i, b16);
        float pof = ld(phs,  (size_t)n * 4 + i, b16);

        float mean  = sx[i] * (1.0f / KNB);
        float var   = fmaxf((sxx[i] - (float)KNB * mean * mean) * (1.0f / (KNB - 1)), 0.0f);
        float afa   = 0.25f / (1.0f + 0.1f * var);
        float amp_s = (1.0f - afa) * aof + afa * swx[i];

        float cons = sqrtf(wre[i] * wre[i] + wim[i] * wim[i]);
        float afp  = 0.15f * cons;
        float s, c;
        __sincosf(pof, &s, &c);
        float mre = (1.0f - afp) * c + afp * wre[i];
        float mim = (1.0f - afp) * s + afp * wim[i];
        float h   = sqrtf(mre * mre + mim * mim);
        float ai, bi;
        if (h > 1e-30f) {
            float scale = amp_s / h;
            ai = mre * scale;
            bi = mim * scale;
        } else {  // atan2(0,0)=0 -> cos=1, sin=0
            ai = amp_s;
            bi = 0.0f;
        }
        outp[2 + i] = ai;
        outp[6 + i] = bi;
    }
}

__device__ __forceinline__ void synth_row_store(
    void* out, size_t o, float v, bool b16)
{
    if (b16) ((unsigned short*)out)[o] = f2bf(v);
    else     ((float*)out)[o] = v;
}

// ---------------- r8: fused, 1 wave/block, all threads active ---------------
// 64 threads, 64 rows/block. Phase 1: thread tid computes params for row
// row0+tid (EXACT smooth_kernel per-thread pattern). Phase 2: thread tid owns
// time columns {tid, tid+64, ..., tid+320} (guard t<365), loops the block's
// rows reading params from LDS (broadcast reads, conflict-free).

#define NCOL 6   // ceil(365/64)

__global__ __launch_bounds__(64) void fused64_kernel(
    const void* __restrict__ amps,
    const void* __restrict__ phs,
    const void* __restrict__ wgts,
    const int*  __restrict__ idx,
    const void* __restrict__ coff,
    const void* __restrict__ trend,
    const void* __restrict__ tvec,
    void*       __restrict__ out)
{
    __shared__ float P[FUSED_ROWS][12];
    bool b16 = detect_bf16(tvec);

    int row0 = blockIdx.x * FUSED_ROWS;
    int tid  = threadIdx.x;

    int n = row0 + tid;
    if (n < N_PTS) {
        float outp[12];
        compute_params(n, b16, amps, phs, wgts, idx, coff, trend, outp);
        #pragma unroll
        for (int i = 0; i < 12; ++i) P[tid][i] = outp[i];
    }
    __syncthreads();

    const float W0 = 25.132741228718345f;   // 2*pi*4
    const float W1 = 12.566370614359172f;   // 2*pi*2
    const float W2 = 6.283185307179586f;    // 2*pi*1
    const float W3 = 3.141592653589793f;    // 2*pi*0.5

    // Per-thread column set: precompute tval + 4 sincos pairs per column.
    float tv[NCOL];
    float s0[NCOL], c0[NCOL], s1[NCOL], c1[NCOL];
    float s2[NCOL], c2[NCOL], s3[NCOL], c3[NCOL];
    #pragma unroll
    for (int c = 0; c < NCOL; ++c) {
        int t = tid + 64 * c;
        float tval = (t < TLEN) ? ld(tvec, t, b16) : 0.0f;
        tv[c] = tval;
        __sincosf(W0 * tval, &s0[c], &c0[c]);
        __sincosf(W1 * tval, &s1[c], &c1[c]);
        __sincosf(W2 * tval, &s2[c], &c2[c]);
        __sincosf(W3 * tval, &s3[c], &c3[c]);
    }

    int rend = min(row0 + FUSED_ROWS, N_PTS) - row0;
    for (int r = 0; r < rend; ++r) {
        float p0 = P[r][0], p1 = P[r][1];
        float p2 = P[r][2], p3 = P[r][3], p4 = P[r][4], p5 = P[r][5];
        float p6 = P[r][6], p7 = P[r][7], p8 = P[r][8], p9 = P[r][9];
        size_t base = (size_t)(row0 + r) * TLEN;
        #pragma unroll
        for (int c = 0; c < NCOL; ++c) {
            int t = tid + 64 * c;
            if (t < TLEN) {
                float v = fmaf(p1, tv[c], p0);
                v = fmaf(p2, s0[c], v);
                v = fmaf(p3, s1[c], v);
                v = fmaf(p4, s2[c], v);
                v = fmaf(p5, s3[c], v);
                v = fmaf(p6, c0[c], v);
                v = fmaf(p7, c1[c], v);
                v = fmaf(p8, c2[c], v);
                v = fmaf(p9, c3[c], v);
                synth_row_store(out, base + t, v, b16);
            }
        }
    }
}

// ---------------- Path A: two kernels via d_ws (r7, kept as fallback) ------

__global__ __launch_bounds__(256) void smooth_kernel(
    const void* __restrict__ amps,
    const void* __restrict__ phs,
    const void* __restrict__ wgts,
    const int*  __restrict__ idx,
    const void* __restrict__ coff,
    const void* __restrict__ trend,
    const void* __restrict__ tvec,
    float*      __restrict__ params)
{
    int n = blockIdx.x * blockDim.x + threadIdx.x;
    if (n >= N_PTS) return;
    bool b16 = detect_bf16(tvec);
    float outp[12];
    compute_params(n, b16, amps, phs, wgts, idx, coff, trend, outp);
    #pragma unroll
    for (int i = 0; i < 12; ++i) params[(size_t)n * 12 + i] = outp[i];
}

__global__ __launch_bounds__(384) void synth_kernel(
    const float* __restrict__ params,
    const void*  __restrict__ tvec,
    void*        __restrict__ out)
{
    bool b16 = detect_bf16(tvec);
    int t = threadIdx.x;
    if (t >= TLEN) return;
    float tval = ld(tvec, t, b16);

    const float W0 = 25.132741228718345f;
    const float W1 = 12.566370614359172f;
    const float W2 = 6.283185307179586f;
    const float W3 = 3.141592653589793f;
    float s0, c0, s1, c1, s2, c2, s3, c3;
    __sincosf(W0 * tval, &s0, &c0);
    __sincosf(W1 * tval, &s1, &c1);
    __sincosf(W2 * tval, &s2, &c2);
    __sincosf(W3 * tval, &s3, &c3);

    int row0 = blockIdx.x * SYNTH_ROWS;
    int rend = min(row0 + SYNTH_ROWS, N_PTS);
    for (int n = row0; n < rend; ++n) {
        const float* p = params + (size_t)n * 12;
        float v = fmaf(p[1], tval, p[0]);
        v = fmaf(p[2], s0, v);
        v = fmaf(p[3], s1, v);
        v = fmaf(p[4], s2, v);
        v = fmaf(p[5], s3, v);
        v = fmaf(p[6], c0, v);
        v = fmaf(p[7], c1, v);
        v = fmaf(p[8], c2, v);
        v = fmaf(p[9], c3, v);
        synth_row_store(out, (size_t)n * TLEN + t, v, b16);
    }
}

extern "C" void kernel_launch(void* const* d_in, const int* in_sizes, int n_in,
                              void* d_out, int out_size, void* d_ws, size_t ws_size,
                              hipStream_t stream) {
    const void* tvec  = d_in[0];             // time_vector (365)
    const void* coff  = d_in[1];             // constant_offset (N)
    const void* trend = d_in[2];             // linear_trend (N)
    const void* amps  = d_in[3];             // seasonal_amplitudes (N,4)
    const void* phs   = d_in[4];             // seasonal_phases (N,4)
    const void* wgts  = d_in[5];             // neighbor_weights (N,12)
    const int*  idx   = (const int*)d_in[6]; // neighbor_indices (N,12) int32

    // r8: always fused — no global barrier between param and synth phases,
    // no params round-trip, one launch. Workspace ignored.
    int fblk = (N_PTS + FUSED_ROWS - 1) / FUSED_ROWS;  // 1563
    fused64_kernel<<<fblk, 64, 0, stream>>>(
        amps, phs, wgts, idx, coff, trend, tvec, d_out);
}

// Round 2
// 222.973 us; speedup vs baseline: 1.0087x; 1.0026x over previous
//
#include <hip/hip_runtime.h>

#define N_PTS 100000
#define KNB   12
#define TLEN  365
#define FUSED_ROWS 64
#define SYNTH_ROWS 16
#define PARAMS_BYTES ((size_t)N_PTS * 12 * sizeof(float))

// ENVIRONMENT FACTS (rounds 0-8):
//  - Inputs are bf16 (runtime probe, absmax 0.0625 = bf16 floor). idx int32.
//    Output buffer is bf16 (73 MB): in_npz 11.2MB matches bf16 inputs; ref
//    npz is fp32 but our bf16 stores pass => d_out is bf16, compared w/ tol.
//  - compute_params (incl. ALL load code) is load-bearing: rounds 4-6
//    changed the per-thread/per-pixel pattern + hardcoded bf16 -> NaN.
//    Only launch geometry / non-load code may change.
//  - r8 (223.5 us): fused64 = 88-91 us standalone. VALUBusy 14.5%,
//    HBM 24.6%, Occupancy 13.8% => latency-bound. Phase-1 TLP is pinned
//    (1563 waves total, ~6/CU). VGPR_Count=64 (launch_bounds(64)) starves
//    MLP: the 12x8 unrolled gather loop serializes into small batches.
//  - r9 (this round): __launch_bounds__(64,1) releases VGPR budget (grid-
//    limited occupancy => regs free up to ~256); #pragma unroll 2 on the
//    phase-2 row loop batches ds_reads. compute_params untouched.

__device__ __forceinline__ float bf2f(unsigned short u) {
    return __uint_as_float(((unsigned int)u) << 16);
}
__device__ __forceinline__ unsigned short f2bf(float f) {
    unsigned int x = __float_as_uint(f);
    unsigned int r = (x + 0x7FFFu + ((x >> 16) & 1u)) >> 16;
    return (unsigned short)r;
}

// Runtime input-dtype detection: time_vector[0] == 0.0 exactly.
__device__ __forceinline__ bool detect_bf16(const void* tvec) {
    return ((const unsigned int*)tvec)[0] != 0u;
}

// Scalar dual-dtype load (round-3 proven).
__device__ __forceinline__ float ld(const void* p, size_t i, bool b16) {
    if (b16) return bf2f(((const unsigned short*)p)[i]);
    return ((const float*)p)[i];
}

// Param row for pixel n: [c, trend, a0..a3, b0..b3]  (round-3 verbatim)
__device__ void compute_params(
    int n, bool b16,
    const void* __restrict__ amps,
    const void* __restrict__ phs,
    const void* __restrict__ wgts,
    const int*  __restrict__ idx,
    const void* __restrict__ coff,
    const void* __restrict__ trend,
    float outp[12])
{
    float sx[4]  = {0,0,0,0}, sxx[4] = {0,0,0,0}, swx[4] = {0,0,0,0};
    float wre[4] = {0,0,0,0}, wim[4] = {0,0,0,0};

    #pragma unroll
    for (int k = 0; k < KNB; ++k) {
        int j = idx[(size_t)n * KNB + k];
        j = (j < 0) ? 0 : ((j >= N_PTS) ? N_PTS - 1 : j);  // defensive clamp
        float wk = ld(wgts, (size_t)n * KNB + k, b16);
        #pragma unroll
        for (int i = 0; i < 4; ++i) {
            float a = ld(amps, (size_t)j * 4 + i, b16);
            float p = ld(phs,  (size_t)j * 4 + i, b16);
            sx[i]  += a;
            sxx[i] += a * a;
            swx[i] += wk * a;
            float s, c;
            __sincosf(p, &s, &c);
            wre[i] += wk * c;
            wim[i] += wk * s;
        }
    }

    outp[0] = ld(coff,  n, b16);
    outp[1] = ld(trend, n, b16);
    #pragma unroll
    for (int i = 0; i < 4; ++i) {
        float aof = ld(amps, (size_t)n * 4 + i, b16);
        float pof = ld(phs,  (size_t)n * 4 + i, b16);

        float mean  = sx[i] * (1.0f / KNB);
        float var   = fmaxf((sxx[i] - (float)KNB * mean * mean) * (1.0f / (KNB - 1)), 0.0f);
        float afa   = 0.25f / (1.0f + 0.1f * var);
        float amp_s = (1.0f - afa) * aof + afa * swx[i];

        float cons = sqrtf(wre[i] * wre[i] + wim[i] * wim[i]);
        float afp  = 0.15f * cons;
        float s, c;
        __sincosf(pof, &s, &c);
        float mre = (1.0f - afp) * c + afp * wre[i];
        float mim = (1.0f - afp) * s + afp * wim[i];
        float h   = sqrtf(mre * mre + mim * mim);
        float ai, bi;
        if (h > 1e-30f) {
            float scale = amp_s / h;
            ai = mre * scale;
            bi = mim * scale;
        } else {  // atan2(0,0)=0 -> cos=1, sin=0
            ai = amp_s;
            bi = 0.0f;
        }
        outp[2 + i] = ai;
        outp[6 + i] = bi;
    }
}

__device__ __forceinline__ void synth_row_store(
    void* out, size_t o, float v, bool b16)
{
    if (b16) ((unsigned short*)out)[o] = f2bf(v);
    else     ((float*)out)[o] = v;
}

// ---------------- r9: fused, 1 wave/block, unrestricted VGPR budget ---------
// 64 threads, 64 rows/block. Phase 1: thread tid computes params for row
// row0+tid (EXACT smooth_kernel per-thread pattern). Phase 2: thread tid owns
// time columns {tid, tid+64, ..., tid+320} (guard t<365), loops the block's
// rows reading params from LDS (broadcast reads, conflict-free).

#define NCOL 6   // ceil(365/64)

__global__ __launch_bounds__(64, 1) void fused64_kernel(
    const void* __restrict__ amps,
    const void* __restrict__ phs,
    const void* __restrict__ wgts,
    const int*  __restrict__ idx,
    const void* __restrict__ coff,
    const void* __restrict__ trend,
    const void* __restrict__ tvec,
    void*       __restrict__ out)
{
    __shared__ float P[FUSED_ROWS][12];
    bool b16 = detect_bf16(tvec);

    int row0 = blockIdx.x * FUSED_ROWS;
    int tid  = threadIdx.x;

    int n = row0 + tid;
    if (n < N_PTS) {
        float outp[12];
        compute_params(n, b16, amps, phs, wgts, idx, coff, trend, outp);
        #pragma unroll
        for (int i = 0; i < 12; ++i) P[tid][i] = outp[i];
    }
    __syncthreads();

    const float W0 = 25.132741228718345f;   // 2*pi*4
    const float W1 = 12.566370614359172f;   // 2*pi*2
    const float W2 = 6.283185307179586f;    // 2*pi*1
    const float W3 = 3.141592653589793f;    // 2*pi*0.5

    // Per-thread column set: precompute tval + 4 sincos pairs per column.
    float tv[NCOL];
    float s0[NCOL], c0[NCOL], s1[NCOL], c1[NCOL];
    float s2[NCOL], c2[NCOL], s3[NCOL], c3[NCOL];
    #pragma unroll
    for (int c = 0; c < NCOL; ++c) {
        int t = tid + 64 * c;
        float tval = (t < TLEN) ? ld(tvec, t, b16) : 0.0f;
        tv[c] = tval;
        __sincosf(W0 * tval, &s0[c], &c0[c]);
        __sincosf(W1 * tval, &s1[c], &c1[c]);
        __sincosf(W2 * tval, &s2[c], &c2[c]);
        __sincosf(W3 * tval, &s3[c], &c3[c]);
    }

    int rend = min(row0 + FUSED_ROWS, N_PTS) - row0;
    #pragma unroll 2
    for (int r = 0; r < rend; ++r) {
        float p0 = P[r][0], p1 = P[r][1];
        float p2 = P[r][2], p3 = P[r][3], p4 = P[r][4], p5 = P[r][5];
        float p6 = P[r][6], p7 = P[r][7], p8 = P[r][8], p9 = P[r][9];
        size_t base = (size_t)(row0 + r) * TLEN;
        #pragma unroll
        for (int c = 0; c < NCOL; ++c) {
            int t = tid + 64 * c;
            if (t < TLEN) {
                float v = fmaf(p1, tv[c], p0);
                v = fmaf(p2, s0[c], v);
                v = fmaf(p3, s1[c], v);
                v = fmaf(p4, s2[c], v);
                v = fmaf(p5, s3[c], v);
                v = fmaf(p6, c0[c], v);
                v = fmaf(p7, c1[c], v);
                v = fmaf(p8, c2[c], v);
                v = fmaf(p9, c3[c], v);
                synth_row_store(out, base + t, v, b16);
            }
        }
    }
}

// ---------------- Path A: two kernels via d_ws (kept as fallback) -----------

__global__ __launch_bounds__(256) void smooth_kernel(
    const void* __restrict__ amps,
    const void* __restrict__ phs,
    const void* __restrict__ wgts,
    const int*  __restrict__ idx,
    const void* __restrict__ coff,
    const void* __restrict__ trend,
    const void* __restrict__ tvec,
    float*      __restrict__ params)
{
    int n = blockIdx.x * blockDim.x + threadIdx.x;
    if (n >= N_PTS) return;
    bool b16 = detect_bf16(tvec);
    float outp[12];
    compute_params(n, b16, amps, phs, wgts, idx, coff, trend, outp);
    #pragma unroll
    for (int i = 0; i < 12; ++i) params[(size_t)n * 12 + i] = outp[i];
}

__global__ __launch_bounds__(384) void synth_kernel(
    const float* __restrict__ params,
    const void*  __restrict__ tvec,
    void*        __restrict__ out)
{
    bool b16 = detect_bf16(tvec);
    int t = threadIdx.x;
    if (t >= TLEN) return;
    float tval = ld(tvec, t, b16);

    const float W0 = 25.132741228718345f;
    const float W1 = 12.566370614359172f;
    const float W2 = 6.283185307179586f;
    const float W3 = 3.141592653589793f;
    float s0, c0, s1, c1, s2, c2, s3, c3;
    __sincosf(W0 * tval, &s0, &c0);
    __sincosf(W1 * tval, &s1, &c1);
    __sincosf(W2 * tval, &s2, &c2);
    __sincosf(W3 * tval, &s3, &c3);

    int row0 = blockIdx.x * SYNTH_ROWS;
    int rend = min(row0 + SYNTH_ROWS, N_PTS);
    for (int n = row0; n < rend; ++n) {
        const float* p = params + (size_t)n * 12;
        float v = fmaf(p[1], tval, p[0]);
        v = fmaf(p[2], s0, v);
        v = fmaf(p[3], s1, v);
        v = fmaf(p[4], s2, v);
        v = fmaf(p[5], s3, v);
        v = fmaf(p[6], c0, v);
        v = fmaf(p[7], c1, v);
        v = fmaf(p[8], c2, v);
        v = fmaf(p[9], c3, v);
        synth_row_store(out, (size_t)n * TLEN + t, v, b16);
    }
}

extern "C" void kernel_launch(void* const* d_in, const int* in_sizes, int n_in,
                              void* d_out, int out_size, void* d_ws, size_t ws_size,
                              hipStream_t stream) {
    const void* tvec  = d_in[0];             // time_vector (365)
    const void* coff  = d_in[1];             // constant_offset (N)
    const void* trend = d_in[2];             // linear_trend (N)
    const void* amps  = d_in[3];             // seasonal_amplitudes (N,4)
    const void* phs   = d_in[4];             // seasonal_phases (N,4)
    const void* wgts  = d_in[5];             // neighbor_weights (N,12)
    const int*  idx   = (const int*)d_in[6]; // neighbor_indices (N,12) int32

    // Fused: no global barrier between param and synth phases, no params
    // round-trip, one launch. Workspace ignored.
    int fblk = (N_PTS + FUSED_ROWS - 1) / FUSED_ROWS;  // 1563
    fused64_kernel<<<fblk, 64, 0, stream>>>(
        amps, phs, wgts, idx, coff, trend, tvec, d_out);
}

// Round 3
// 194.169 us; speedup vs baseline: 1.1583x; 1.1483x over previous
//
#include <hip/hip_runtime.h>

#define N_PTS 100000
#define KNB   12
#define TLEN  365
#define ROWS  16     // rows per 64-thread block; 6250 blocks, no tail
#define NCOL  6      // ceil(365/64)

// ENVIRONMENT FACTS (rounds 0-10):
//  - r10 DISCOVERY: detect_bf16 probes tvec[0], which is 0.0 => bits
//    0x00000000 in EITHER dtype => detect has ALWAYS returned false => the
//    kernel has ALWAYS executed the fp32 path and passed. r9 counters
//    confirm: WRITE_SIZE = 142578 KB = exactly N*T*4 (fp32 output).
//    => inputs fp32, output fp32. absmax 0.0625 = __sincosf approx error
//    (args up to ~25 rad, values up to ~16), NOT bf16 quantization.
//    => rounds 4-6 NaN mechanism SOLVED: they hard-coded the bf16 path,
//    reinterpreting fp32 data as bf16. Load code is NOT magic; only the
//    dtype was wrong. bf16 fallback kept (scalar, verbatim) for safety.
//  - r8/r9 (223 us): fused64 = 87-91 us standalone; VALUBusy 15%, HBM 25%,
//    Occ 14% => latency-bound, TLP-starved (1563 waves). launch_bounds(64,1)
//    did NOT raise VGPR use (stayed 64) => compiler won't pipeline harder on
//    its own; restructure instead.
//  - r10 (this round): (1) float4 gathers for amps/phs (96 scalar -> 24
//    vector gathers, TA probes /4, bitwise-identical accumulation order);
//    (2) ROWS 64 -> 16: 6250 single-wave blocks, ~24 waves/CU; (3) params
//    broadcast via v_readlane from lanes 0-15 (block = 1 wave) -> no LDS,
//    no barrier. Real-work floor ~= 23 us store-BW + gather traffic.

__device__ __forceinline__ float bf2f(unsigned short u) {
    return __uint_as_float(((unsigned int)u) << 16);
}
__device__ __forceinline__ unsigned short f2bf(float f) {
    unsigned int x = __float_as_uint(f);
    unsigned int r = (x + 0x7FFFu + ((x >> 16) & 1u)) >> 16;
    return (unsigned short)r;
}

// Runtime input-dtype detection (always false in practice; see facts above).
__device__ __forceinline__ bool detect_bf16(const void* tvec) {
    return ((const unsigned int*)tvec)[0] != 0u;
}

// Scalar dual-dtype load.
__device__ __forceinline__ float ld(const void* p, size_t i, bool b16) {
    if (b16) return bf2f(((const unsigned short*)p)[i]);
    return ((const float*)p)[i];
}

// Wave-uniform lane broadcast: VGPR -> SGPR, no LDS traffic.
__device__ __forceinline__ float rl(float v, int lane) {
    return __int_as_float(__builtin_amdgcn_readlane(__float_as_int(v), lane));
}

// Param row for pixel n: [c, trend, a0..a3, b0..b3] in outp[0..9].
// Same arithmetic and accumulation order as the round-3 kernel; only the
// load WIDTH changed on the fp32 path (float4 instead of 4x scalar).
__device__ void compute_params(
    int n, bool b16,
    const void* __restrict__ amps,
    const void* __restrict__ phs,
    const void* __restrict__ wgts,
    const int*  __restrict__ idx,
    const void* __restrict__ coff,
    const void* __restrict__ trend,
    float outp[12])
{
    float sx[4]  = {0,0,0,0}, sxx[4] = {0,0,0,0}, swx[4] = {0,0,0,0};
    float wre[4] = {0,0,0,0}, wim[4] = {0,0,0,0};

    // Neighbor indices: int32 regardless of dtype. Row starts at n*48 B
    // (16B-aligned) -> 3x int4.
    int jj[KNB];
    {
        const int4* i4 = (const int4*)(idx + (size_t)n * KNB);
        #pragma unroll
        for (int q = 0; q < 3; ++q) {
            int4 v = i4[q];
            jj[q*4+0] = v.x; jj[q*4+1] = v.y; jj[q*4+2] = v.z; jj[q*4+3] = v.w;
        }
    }
    // Weights: fp32 row = 48 B, 16B-aligned -> 3x float4 (scalar bf16 fallback).
    float wk[KNB];
    if (!b16) {
        const float4* w4 = (const float4*)((const float*)wgts + (size_t)n * KNB);
        #pragma unroll
        for (int q = 0; q < 3; ++q) {
            float4 v = w4[q];
            wk[q*4+0] = v.x; wk[q*4+1] = v.y; wk[q*4+2] = v.z; wk[q*4+3] = v.w;
        }
    } else {
        #pragma unroll
        for (int k = 0; k < KNB; ++k) wk[k] = ld(wgts, (size_t)n * KNB + k, true);
    }

    #pragma unroll
    for (int k = 0; k < KNB; ++k) {
        int j = jj[k];
        j = (j < 0) ? 0 : ((j >= N_PTS) ? N_PTS - 1 : j);  // defensive clamp
        float wkk = wk[k];
        float av[4], pv[4];
        if (!b16) {
            // amps/phs row j: 4 floats, 16B-aligned -> one float4 gather each.
            float4 a4 = *(const float4*)((const float*)amps + (size_t)j * 4);
            float4 p4 = *(const float4*)((const float*)phs  + (size_t)j * 4);
            av[0] = a4.x; av[1] = a4.y; av[2] = a4.z; av[3] = a4.w;
            pv[0] = p4.x; pv[1] = p4.y; pv[2] = p4.z; pv[3] = p4.w;
        } else {
            #pragma unroll
            for (int i = 0; i < 4; ++i) {
                av[i] = ld(amps, (size_t)j * 4 + i, true);
                pv[i] = ld(phs,  (size_t)j * 4 + i, true);
            }
        }
        #pragma unroll
        for (int i = 0; i < 4; ++i) {
            float a = av[i], p = pv[i];
            sx[i]  += a;
            sxx[i] += a * a;
            swx[i] += wkk * a;
            float s, c;
            __sincosf(p, &s, &c);
            wre[i] += wkk * c;
            wim[i] += wkk * s;
        }
    }

    outp[0] = ld(coff,  n, b16);
    outp[1] = ld(trend, n, b16);

    float aof4[4], pof4[4];
    if (!b16) {
        float4 a4 = *(const float4*)((const float*)amps + (size_t)n * 4);
        float4 p4 = *(const float4*)((const float*)phs  + (size_t)n * 4);
        aof4[0] = a4.x; aof4[1] = a4.y; aof4[2] = a4.z; aof4[3] = a4.w;
        pof4[0] = p4.x; pof4[1] = p4.y; pof4[2] = p4.z; pof4[3] = p4.w;
    } else {
        #pragma unroll
        for (int i = 0; i < 4; ++i) {
            aof4[i] = ld(amps, (size_t)n * 4 + i, true);
            pof4[i] = ld(phs,  (size_t)n * 4 + i, true);
        }
    }

    #pragma unroll
    for (int i = 0; i < 4; ++i) {
        float aof = aof4[i];
        float pof = pof4[i];

        float mean  = sx[i] * (1.0f / KNB);
        float var   = fmaxf((sxx[i] - (float)KNB * mean * mean) * (1.0f / (KNB - 1)), 0.0f);
        float afa   = 0.25f / (1.0f + 0.1f * var);
        float amp_s = (1.0f - afa) * aof + afa * swx[i];

        float cons = sqrtf(wre[i] * wre[i] + wim[i] * wim[i]);
        float afp  = 0.15f * cons;
        float s, c;
        __sincosf(pof, &s, &c);
        float mre = (1.0f - afp) * c + afp * wre[i];
        float mim = (1.0f - afp) * s + afp * wim[i];
        float h   = sqrtf(mre * mre + mim * mim);
        float ai, bi;
        if (h > 1e-30f) {
            float scale = amp_s / h;
            ai = mre * scale;
            bi = mim * scale;
        } else {  // atan2(0,0)=0 -> cos=1, sin=0
            ai = amp_s;
            bi = 0.0f;
        }
        outp[2 + i] = ai;
        outp[6 + i] = bi;
    }
}

__device__ __forceinline__ void synth_row_store(
    void* out, size_t o, float v, bool b16)
{
    if (b16) ((unsigned short*)out)[o] = f2bf(v);
    else     ((float*)out)[o] = v;
}

// ---------------- r10: fused, 16 rows / 64-thread block, no LDS -------------
// Phase 1: lanes 0..15 each compute one row's params (masked-subset call,
// round-3-proven shape). Phase 2: params broadcast from lane r via
// v_readlane (block = 1 wave, program order guarantees phase-1 writes are
// done); each thread owns time columns {tid, tid+64, ...}.

__global__ __launch_bounds__(64, 1) void fused_r16_kernel(
    const void* __restrict__ amps,
    const void* __restrict__ phs,
    const void* __restrict__ wgts,
    const int*  __restrict__ idx,
    const void* __restrict__ coff,
    const void* __restrict__ trend,
    const void* __restrict__ tvec,
    void*       __restrict__ out)
{
    bool b16 = detect_bf16(tvec);
    int tid  = threadIdx.x;
    int row0 = blockIdx.x * ROWS;

    float outp[12] = {0,0,0,0,0,0,0,0,0,0,0,0};
    int n = row0 + tid;
    if (tid < ROWS && n < N_PTS) {
        compute_params(n, b16, amps, phs, wgts, idx, coff, trend, outp);
    }

    const float W0 = 25.132741228718345f;   // 2*pi*4
    const float W1 = 12.566370614359172f;   // 2*pi*2
    const float W2 = 6.283185307179586f;    // 2*pi*1
    const float W3 = 3.141592653589793f;    // 2*pi*0.5

    float tv[NCOL];
    float s0[NCOL], c0[NCOL], s1[NCOL], c1[NCOL];
    float s2[NCOL], c2[NCOL], s3[NCOL], c3[NCOL];
    #pragma unroll
    for (int cc = 0; cc < NCOL; ++cc) {
        int t = tid + 64 * cc;
        float tval = (t < TLEN) ? ld(tvec, t, b16) : 0.0f;
        tv[cc] = tval;
        __sincosf(W0 * tval, &s0[cc], &c0[cc]);
        __sincosf(W1 * tval, &s1[cc], &c1[cc]);
        __sincosf(W2 * tval, &s2[cc], &c2[cc]);
        __sincosf(W3 * tval, &s3[cc], &c3[cc]);
    }

    int rend = min(row0 + ROWS, N_PTS) - row0;
    for (int r = 0; r < rend; ++r) {
        // Broadcast row r's params from lane r (uniform lane -> v_readlane).
        float p0 = rl(outp[0], r);
        float p1 = rl(outp[1], r);
        float p2 = rl(outp[2], r);
        float p3 = rl(outp[3], r);
        float p4 = rl(outp[4], r);
        float p5 = rl(outp[5], r);
        float p6 = rl(outp[6], r);
        float p7 = rl(outp[7], r);
        float p8 = rl(outp[8], r);
        float p9 = rl(outp[9], r);
        size_t base = (size_t)(row0 + r) * TLEN;
        #pragma unroll
        for (int cc = 0; cc < NCOL; ++cc) {
            int t = tid + 64 * cc;
            if (t < TLEN) {
                float v = fmaf(p1, tv[cc], p0);
                v = fmaf(p2, s0[cc], v);
                v = fmaf(p3, s1[cc], v);
                v = fmaf(p4, s2[cc], v);
                v = fmaf(p5, s3[cc], v);
                v = fmaf(p6, c0[cc], v);
                v = fmaf(p7, c1[cc], v);
                v = fmaf(p8, c2[cc], v);
                v = fmaf(p9, c3[cc], v);
                synth_row_store(out, base + t, v, b16);
            }
        }
    }
}

extern "C" void kernel_launch(void* const* d_in, const int* in_sizes, int n_in,
                              void* d_out, int out_size, void* d_ws, size_t ws_size,
                              hipStream_t stream) {
    const void* tvec  = d_in[0];             // time_vector (365)
    const void* coff  = d_in[1];             // constant_offset (N)
    const void* trend = d_in[2];             // linear_trend (N)
    const void* amps  = d_in[3];             // seasonal_amplitudes (N,4)
    const void* phs   = d_in[4];             // seasonal_phases (N,4)
    const void* wgts  = d_in[5];             // neighbor_weights (N,12)
    const int*  idx   = (const int*)d_in[6]; // neighbor_indices (N,12) int32

    int fblk = (N_PTS + ROWS - 1) / ROWS;    // 6250, no tail
    fused_r16_kernel<<<fblk, 64, 0, stream>>>(
        amps, phs, wgts, idx, coff, trend, tvec, d_out);
}